// Round 9
// baseline (293.573 us; speedup 1.0000x reference)
//
#include <hip/hip_runtime.h>

typedef __attribute__((ext_vector_type(8))) short bf16x8;
typedef __attribute__((ext_vector_type(4))) float f32x4;
typedef __attribute__((ext_vector_type(4))) unsigned short us4;

#define AS1 __attribute__((address_space(1)))
#define AS3 __attribute__((address_space(3)))

__device__ __forceinline__ unsigned short f2bf(float f) {
  unsigned u = __float_as_uint(f);
  u += 0x7fff + ((u >> 16) & 1);   // RNE
  return (unsigned short)(u >> 16);
}

__device__ __forceinline__ void gload_lds16(const void* g, void* l) {
  __builtin_amdgcn_global_load_lds((const AS1 unsigned int*)g,
                                   (AS3 unsigned int*)l, 16, 0, 0);
}

#define MFMA16(a, b, c) __builtin_amdgcn_mfma_f32_16x16x32_bf16(a, b, c, 0, 0, 0)

// ---------------------------------------------------------------------------
// BM x 128, BK=32 bf16 GEMM, 128x64 WAVE TILE (round-9), one window per
// K-tile, 3-deep LDS ring.  C[M,N] = scale*(A[M,K] @ Bt[N,K]^T) + bias.
// Variant A: BM=256, THREADS=256 (4 waves, 2x2 of 128x64), 72 KB -> 2 blk/CU.
// Variant B: BM=128, THREADS=128 (2 waves, 1x2 of 128x64), 48 KB -> 3 blk/CU.
// Per-wave: acc[8][4] (128 f32, AGPR), af[8]+bf[4] reads = 12 KB per 32 MFMA
// -> LDS-read bytes/FLOP 25% lower than the 64x64 tile, and per-window fixed
// costs amortize over 2x MFMA.
//
// LDS layout (round-7, verified 0 conflicts + coalesced staging): row-major
// 16-row x 32-col fragment blocks (1 KB); 16B chunk index XORed with
// g(row) = (row>>1)&3.
// Stage: one gload/thread per call of RPC = THREADS/4 rows; lane tid fetches
//   global row = r0 + tid>>2, chunk = (tid&3) ^ ((tid>>3)&3)  [== g(row),
//   r0 multiple of 32 doesn't perturb g]
//   -> each 4-lane quad covers one full (permuted) 64B line => coalesced;
//   LDS dest = callbase + tid*16B (linear, rule 21).
// Read: lane (l15, hi) reads block offset l15*64B + (hi ^ g(l15))*16B
//   -> same bank distribution as linear (verified SQ_LDS_BANK_CONFLICT=0).
// Calls/tile: A: BM/RPC = 4, B: 128/RPC -> LOADS = 6 (A) / 8 (B).
//
// Window t: stage(t+2) [LOADS gloads] ; ds_read af[8], bf[4] of tile t ;
// 32 MFMA ; vmcnt(LOADS) ; s_barrier.
//   Steady state at wait: outstanding = 2*LOADS -> vmcnt(LOADS) drains
//   exactly stage(t+1), one full window ahead of its reads.  Per-wave vmcnt
//   + barrier => tile complete CU-wide.  Tail: t+2==NT -> vmcnt(0); last
//   window -> no wait.
// WAR: stage(t+2) overwrites buf[(t-1)%3]; its ds_reads were lgkm-drained
// before window t-1's MFMAs, then the end-of-(t-1) barrier was crossed.
//
// MODE 0: C[bz*sC + row*ldc + col].  MODE 1 (fused QKV, variant A only):
// piece = col0>>10 (wave-uniform); pieces 0,1 -> compact [8192][1024] at
// C + piece*sC; piece 2 -> V transposed to Vt[b][d][2048], b = blockIdx.x>>3.
// ---------------------------------------------------------------------------
template <typename OutT, bool BIAS, int MODE, int BM, int THREADS>
__global__ __launch_bounds__(THREADS, 2) void gemmk(
    const unsigned short* __restrict__ A,
    const unsigned short* __restrict__ Bt,
    OutT* __restrict__ C,
    unsigned short* __restrict__ Vt,
    const float* __restrict__ bias,
    int Kd, int lda, int ldb, int ldc,
    long sA, long sB, long sC,
    float scale) {
  constexpr int WAVES  = THREADS / 64;       // 4 or 2
  constexpr int RPC    = THREADS / 4;        // rows per stage call
  constexpr int ACALLS = BM / RPC;           // 4
  constexpr int BCALLS = 128 / RPC;          // 2 or 4
  constexpr int LOADS  = ACALLS + BCALLS;    // 6 or 8
  constexpr int ABUF   = BM * 32;            // ushorts
  constexpr int BUFSZ  = ABUF + 128 * 32;    // ushorts
  __shared__ unsigned short lds[3 * BUFSZ];  // 72 KB / 48 KB

  const int bz = blockIdx.z;
  A  += (size_t)bz * sA + (size_t)blockIdx.x * BM * lda;
  Bt += (size_t)bz * sB + (size_t)blockIdx.y * 128 * ldb;

  const int tid  = threadIdx.x;
  const int wave = tid >> 6;
  const int lane = tid & 63;
  const int wm   = (WAVES == 4) ? (wave >> 1) : 0;   // row half
  const int wn   = wave & 1;                          // col half
  const int l15  = lane & 15;
  const int hi   = lane >> 4;              // 0..3
  // stage-side: lane covers global (row = r0 + tid>>2, chunk = (tid&3)^g)
  const int srow = tid >> 2;
  const int schk = ((tid & 3) ^ ((tid >> 3) & 3)) * 8;  // ushort offset

  auto stage = [&](int bi, int k0) {
    unsigned short* L = &lds[bi * BUFSZ + wave * 512];     // wave-uniform
    const unsigned short* ga = A + (size_t)srow * lda + (k0 + schk);
#pragma unroll
    for (int c = 0; c < ACALLS; ++c)
      gload_lds16(ga + (size_t)(c * RPC) * lda, L + c * RPC * 32);
    const unsigned short* gb = Bt + (size_t)srow * ldb + (k0 + schk);
#pragma unroll
    for (int c = 0; c < BCALLS; ++c)
      gload_lds16(gb + (size_t)(c * RPC) * ldb, L + ABUF + c * RPC * 32);
  };

  f32x4 acc[8][4] = {};

  // prologue: stage tiles 0,1; drain tile 0 (keep tile 1 in flight)
  stage(0, 0);
  stage(1, 32);
  if constexpr (LOADS == 6) asm volatile("s_waitcnt vmcnt(6)" ::: "memory");
  else                      asm volatile("s_waitcnt vmcnt(8)" ::: "memory");
  __builtin_amdgcn_s_barrier();

  const int NT = Kd >> 5;
  int bufi = 0;
  // read-side swizzled chunk offset: (hi ^ g(l15)) * 8 ushorts
  const int xh  = (hi ^ ((l15 >> 1) & 3)) * 8;
  const int rdA = (wm * 128 + l15) * 32 + xh;          // + mt*512
  const int rdB = ABUF + (wn * 64 + l15) * 32 + xh;    // + nt*512
  for (int t = 0; t < NT; ++t) {
    if (t + 2 < NT) {
      int nbi = bufi + 2; if (nbi >= 3) nbi -= 3;
      stage(nbi, (t + 2) << 5);
    }
    const unsigned short* L = &lds[bufi * BUFSZ];
    bf16x8 af[8], bf[4];
#pragma unroll
    for (int mt = 0; mt < 8; ++mt)
      af[mt] = *(const bf16x8*)&L[rdA + mt * 512];
#pragma unroll
    for (int nt = 0; nt < 4; ++nt)
      bf[nt] = *(const bf16x8*)&L[rdB + nt * 512];
    __builtin_amdgcn_s_setprio(1);
#pragma unroll
    for (int mt = 0; mt < 8; ++mt)
#pragma unroll
      for (int nt = 0; nt < 4; ++nt)
        acc[mt][nt] = MFMA16(af[mt], bf[nt], acc[mt][nt]);
    __builtin_amdgcn_s_setprio(0);
    if (t + 2 < NT) {
      if constexpr (LOADS == 6) asm volatile("s_waitcnt vmcnt(6)" ::: "memory");
      else                      asm volatile("s_waitcnt vmcnt(8)" ::: "memory");
    } else if (t + 1 < NT) {
      asm volatile("s_waitcnt vmcnt(0)" ::: "memory");
    }
    __builtin_amdgcn_s_barrier();
    bufi = (bufi + 1 == 3) ? 0 : bufi + 1;
  }

  // ------------------------------- epilogue -------------------------------
  const int hi4  = hi << 2;
  const int row0 = blockIdx.x * BM + wm * 128;
  const int col0 = blockIdx.y * 128 + wn * 64;

  if constexpr (MODE == 1) {
    const int piece = col0 >> 10;                 // wave-uniform
    float bvv[4];
#pragma unroll
    for (int nt = 0; nt < 4; ++nt)
      bvv[nt] = BIAS ? bias[col0 + nt * 16 + l15] : 0.0f;
    if (piece < 2) {
      OutT* dst = C + (size_t)piece * sC;
      const int cb = (col0 & 1023) + l15;
#pragma unroll
      for (int mt = 0; mt < 8; ++mt)
#pragma unroll
        for (int r = 0; r < 4; ++r) {
          const size_t rowoff = (size_t)(row0 + mt * 16 + hi4 + r) * ldc;
#pragma unroll
          for (int nt = 0; nt < 4; ++nt)
            dst[rowoff + cb + nt * 16] = (OutT)f2bf(acc[mt][nt][r] * scale + bvv[nt]);
        }
    } else {
      // V piece: write transposed Vt[b][d][2048]
      const int b = blockIdx.x >> 3;
      const int sb = (blockIdx.x & 7) * 256 + wm * 128 + hi4;
#pragma unroll
      for (int nt = 0; nt < 4; ++nt) {
        const int d = ((col0 + nt * 16) & 1023) + l15;
#pragma unroll
        for (int mt = 0; mt < 8; ++mt) {
          us4 pk;
          pk.x = f2bf(acc[mt][nt][0] * scale + bvv[nt]);
          pk.y = f2bf(acc[mt][nt][1] * scale + bvv[nt]);
          pk.z = f2bf(acc[mt][nt][2] * scale + bvv[nt]);
          pk.w = f2bf(acc[mt][nt][3] * scale + bvv[nt]);
          *(us4*)&Vt[((size_t)b << 21) + (size_t)d * 2048 + sb + mt * 16] = pk;
        }
      }
    }
  } else {
    C += (size_t)bz * sC;
    float bvv[4];
#pragma unroll
    for (int nt = 0; nt < 4; ++nt)
      bvv[nt] = BIAS ? bias[col0 + nt * 16 + l15] : 0.0f;
    const int cb = col0 + l15;
#pragma unroll
    for (int mt = 0; mt < 8; ++mt)
#pragma unroll
      for (int r = 0; r < 4; ++r) {
        const size_t rowoff = (size_t)(row0 + mt * 16 + hi4 + r) * ldc;
#pragma unroll
        for (int nt = 0; nt < 4; ++nt) {
          const float v = acc[mt][nt][r] * scale + bvv[nt];
          if constexpr (sizeof(OutT) == 4)
            C[rowoff + cb + nt * 16] = v;
          else
            C[rowoff + cb + nt * 16] = (OutT)f2bf(v);
        }
      }
  }
}

// fp32 -> bf16 flat convert (4 elems/thread)
__global__ void cvt_x(const float* __restrict__ in, unsigned short* __restrict__ out, int n4) {
  const int i = blockIdx.x * blockDim.x + threadIdx.x;
  if (i < n4) {
    const float4 v = ((const float4*)in)[i];
    uint2 o;
    o.x = (unsigned)f2bf(v.x) | ((unsigned)f2bf(v.y) << 16);
    o.y = (unsigned)f2bf(v.z) | ((unsigned)f2bf(v.w) << 16);
    ((uint2*)out)[i] = o;
  }
}

// All 4 weight matrices (1024x1024 fp32) -> bf16 transposed, one launch.
__global__ void cvtT_w4(const float* __restrict__ Wq, const float* __restrict__ Wk,
                        const float* __restrict__ Wv, const float* __restrict__ Wo,
                        unsigned short* __restrict__ Wqkvb, unsigned short* __restrict__ Wob) {
  __shared__ unsigned short tile[64][65];
  const int z = blockIdx.z;
  const float* in = (z == 0) ? Wq : (z == 1) ? Wk : (z == 2) ? Wv : Wo;
  unsigned short* out = (z == 3) ? Wob : Wqkvb + (size_t)z * 1024 * 1024;
  const int r0 = blockIdx.y * 64, c0 = blockIdx.x * 64;
  for (int i = threadIdx.y; i < 64; i += 4)
    tile[i][threadIdx.x] = f2bf(in[(size_t)(r0 + i) * 1024 + c0 + threadIdx.x]);
  __syncthreads();
  for (int i = threadIdx.y; i < 64; i += 4)
    out[(size_t)(c0 + i) * 1024 + r0 + threadIdx.x] = tile[threadIdx.x][i];
}

// concat bq|bk|bv into bqkv
__global__ void concat_bias(const float* __restrict__ bq, const float* __restrict__ bk,
                            const float* __restrict__ bv, float* __restrict__ dst) {
  const int z = blockIdx.x;
  const float* src = (z == 0) ? bq : (z == 1) ? bk : bv;
  const int i = threadIdx.x;
  ((float4*)(dst + z * 1024))[i] = ((const float4*)src)[i];
}

// Softmax, one WAVE per 2048-elem bf16 row (lane holds 32 elems), pure
// shfl reductions: no LDS, no barriers. 8 rows per 512-thr block.
__global__ __launch_bounds__(512) void softmax_w(unsigned short* __restrict__ scores) {
  const int lane = threadIdx.x & 63;
  unsigned short* p =
      scores + ((size_t)blockIdx.x * 8 + (threadIdx.x >> 6)) * 2048;
  uint4 raw[4];
  float v[32];
#pragma unroll
  for (int g = 0; g < 4; ++g) raw[g] = ((const uint4*)p)[lane + g * 64];
#pragma unroll
  for (int g = 0; g < 4; ++g) {
    v[g * 8 + 0] = __uint_as_float(raw[g].x << 16);
    v[g * 8 + 1] = __uint_as_float(raw[g].x & 0xffff0000u);
    v[g * 8 + 2] = __uint_as_float(raw[g].y << 16);
    v[g * 8 + 3] = __uint_as_float(raw[g].y & 0xffff0000u);
    v[g * 8 + 4] = __uint_as_float(raw[g].z << 16);
    v[g * 8 + 5] = __uint_as_float(raw[g].z & 0xffff0000u);
    v[g * 8 + 6] = __uint_as_float(raw[g].w << 16);
    v[g * 8 + 7] = __uint_as_float(raw[g].w & 0xffff0000u);
  }
  float m = v[0];
#pragma unroll
  for (int i = 1; i < 32; ++i) m = fmaxf(m, v[i]);
#pragma unroll
  for (int off = 32; off; off >>= 1) m = fmaxf(m, __shfl_xor(m, off, 64));
  float s = 0.f;
#pragma unroll
  for (int i = 0; i < 32; ++i) { v[i] = __expf(v[i] - m); s += v[i]; }
#pragma unroll
  for (int off = 32; off; off >>= 1) s += __shfl_xor(s, off, 64);
  const float inv = 1.0f / s;
#pragma unroll
  for (int g = 0; g < 4; ++g) {
    uint4 ov;
    ov.x = (unsigned)f2bf(v[g * 8 + 0] * inv) | ((unsigned)f2bf(v[g * 8 + 1] * inv) << 16);
    ov.y = (unsigned)f2bf(v[g * 8 + 2] * inv) | ((unsigned)f2bf(v[g * 8 + 3] * inv) << 16);
    ov.z = (unsigned)f2bf(v[g * 8 + 4] * inv) | ((unsigned)f2bf(v[g * 8 + 5] * inv) << 16);
    ov.w = (unsigned)f2bf(v[g * 8 + 6] * inv) | ((unsigned)f2bf(v[g * 8 + 7] * inv) << 16);
    ((uint4*)p)[lane + g * 64] = ov;
  }
}

// ---------------------------------------------------------------------------
extern "C" void kernel_launch(void* const* d_in, const int* in_sizes, int n_in,
                              void* d_out, int out_size, void* d_ws, size_t ws_size,
                              hipStream_t stream) {
  const float* x  = (const float*)d_in[0];
  const float* Wq = (const float*)d_in[1];
  const float* bq = (const float*)d_in[2];
  const float* Wk = (const float*)d_in[3];
  const float* bk = (const float*)d_in[4];
  const float* Wv = (const float*)d_in[5];
  const float* bv = (const float*)d_in[6];
  const float* Wo = (const float*)d_in[7];
  const float* bo = (const float*)d_in[8];
  float* out = (float*)d_out;

  char* ws = (char*)d_ws;
  size_t off = 0;
  auto alloc = [&](size_t bytes) { char* p = ws + off; off += (bytes + 255) & ~255UL; return p; };
  unsigned short* xb    = (unsigned short*)alloc(8192UL * 1024 * 2);     // 16 MiB
  unsigned short* Wqkvb = (unsigned short*)alloc(3072UL * 1024 * 2);     // 6 MiB
  unsigned short* Wob   = (unsigned short*)alloc(1024UL * 1024 * 2);     // 2 MiB
  float*          bqkv  = (float*)alloc(3072UL * 4);
  unsigned short* Qb    = (unsigned short*)alloc(8192UL * 1024 * 2);     // 16 MiB (piece 0)
  unsigned short* Kb    = (unsigned short*)alloc(8192UL * 1024 * 2);     // 16 MiB (piece 1, == Qb + sC)
  unsigned short* Vtb   = (unsigned short*)alloc(4UL * 1024 * 2048 * 2); // 16 MiB [b][d][s]
  unsigned short* attn  = (unsigned short*)alloc(8192UL * 2048 * 2);     // 32 MiB bf16 scores
  unsigned short* ctxb  = (unsigned short*)alloc(8192UL * 1024 * 2);     // 16 MiB

  // input convert + all weight transposes + bias concat
  cvt_x<<<2097152 / 256, 256, 0, stream>>>(x, xb, 2097152);
  cvtT_w4<<<dim3(16, 16, 4), dim3(64, 4), 0, stream>>>(Wq, Wk, Wv, Wo, Wqkvb, Wob);
  concat_bias<<<3, 256, 0, stream>>>(bq, bk, bv, bqkv);

  // fused QKV projection: Q,K compact + V transposed to Vtb. 768 blocks.
  gemmk<unsigned short, true, 1, 256, 256><<<dim3(32, 24, 1), 256, 0, stream>>>(
      xb, Wqkvb, Qb, Vtb, bqkv, 1024, 1024, 1024, 1024, 0, 0, 8192L * 1024, 1.0f);

  // scores = (Q @ K^T) / 32 -> bf16, per batch. 512 blocks.
  gemmk<unsigned short, false, 0, 256, 256><<<dim3(8, 16, 4), 256, 0, stream>>>(
      Qb, Kb, attn, nullptr, nullptr, 1024, 1024, 1024, 2048,
      2048L * 1024, 2048L * 1024, 2048L * 2048, 0.03125f);

  // softmax: one wave per row, 8 rows/block, no barriers. 1024 blocks.
  softmax_w<<<1024, 512, 0, stream>>>(attn);

  // ctx = attn @ V (attn lda=2048, Vt is Bt layout). BM=128 2-wave: 512 blocks.
  gemmk<unsigned short, false, 0, 128, 128><<<dim3(16, 8, 4), 128, 0, stream>>>(
      attn, Vtb, ctxb, nullptr, nullptr, 2048, 2048, 2048, 1024,
      2048L * 2048, 1024L * 2048, 2048L * 1024, 1.0f);

  // out = ctx @ Wo + bo (fp32 out). BM=128 2-wave: 512 blocks.
  gemmk<float, true, 0, 128, 128><<<dim3(64, 8, 1), 128, 0, stream>>>(
      ctxb, Wob, out, nullptr, bo, 1024, 1024, 1024, 1024, 0, 0, 0, 1.0f);
}

// Round 10
// 292.104 us; speedup vs baseline: 1.0050x; 1.0050x over previous
//
#include <hip/hip_runtime.h>

typedef __attribute__((ext_vector_type(8))) short bf16x8;
typedef __attribute__((ext_vector_type(4))) float f32x4;
typedef __attribute__((ext_vector_type(4))) unsigned short us4;

#define AS1 __attribute__((address_space(1)))
#define AS3 __attribute__((address_space(3)))

__device__ __forceinline__ unsigned short f2bf(float f) {
  unsigned u = __float_as_uint(f);
  u += 0x7fff + ((u >> 16) & 1);   // RNE
  return (unsigned short)(u >> 16);
}

__device__ __forceinline__ void gload_lds16(const void* g, void* l) {
  __builtin_amdgcn_global_load_lds((const AS1 unsigned int*)g,
                                   (AS3 unsigned int*)l, 16, 0, 0);
}

#define MFMA16(a, b, c) __builtin_amdgcn_mfma_f32_16x16x32_bf16(a, b, c, 0, 0, 0)
#define BARRIER() __builtin_amdgcn_s_barrier()
#define LGKM0() asm volatile("s_waitcnt lgkmcnt(0)" ::: "memory")
#define VMCNT(n) asm volatile("s_waitcnt vmcnt(" #n ")" ::: "memory")

// ---------------------------------------------------------------------------
// gemm8: 256x256, BK=64, 8-phase schedule (m201-style port), 1 blk/CU.
// C[M,N] = scale*(A[M,K] @ Bt[N,K]^T) + bias.  512 thr = 8 waves 2(M)x4(N);
// per-wave 128x64 = acc[8][4] of 16x16x32 MFMA.
// LDS 128 KB: BUF0 (even K-tiles) | BUF1 (odd): each A[256][64]+B[256][64].
//
// Row = 64 bf16 = 8 x 16B chunks; swizzle: chunk c of row r stored at slot
// c ^ (r&7).  Stage call = 64 rows (512 thr, 1 gload): thread tid covers LDS
// (row r0+(tid>>3), slot tid&7), fetching global chunk (tid&7)^((tid>>3)&7)
// -> 8 lanes = one full 128B line (permuted) => coalesced; dest linear.
// Read: lane (l15,hi), kstep ks: slot (ks*4+hi)^(l15&7) -> 8 slots uniform
// over the wave (same distribution class as round-7's verified 0-conflict).
//
// B LDS rows PERMUTED so 64-row stage units match quadrant consumption:
//   lr = nq*128 + (wn>>1)*64 + (wn&1)*32 + (nf*16+l15)  <->
//   gcol = ((lr>>6)&1)*128 + ((lr>>5)&1)*64 + (lr>>7)*32 + (lr&31).
//
// Iteration j consumes K-tiles 2j (BUF0, phases 1-4) and 2j+1 (BUF1, 5-8);
// each phase = one C-quadrant (mq,nq): ph1..4 = (0,0),(0,1),(1,1),(1,0).
// Stage slots (2 gloads/phase; "tX" = K-tile X; guard st = j+1<NP):
//   ph1: t(2j+1) A-mq1     ph2: t(2j+1) B-nq0   [always]
//   ph3: t(2j+2) A-mq0     ph4: t(2j+2) B-nq1
//   ph5: t(2j+2) A-mq1     ph6: t(2j+2) B-nq0
//   ph7: t(2j+3) A-mq0     ph8: t(2j+3) B-nq1
// Deadlines (stage -> first read): 3 phases (B-nq0) or 6 phases (rest).
// WAR: every stage writes a region whose last ds_read was >=1 barrier ago
// (verified per-phase in the derivation; disjoint from concurrent reads).
// Waits: vmcnt(4) at end of ph4 and ph8 ONLY (drains 8 oldest of 12):
//   W4 covers the 4 halves of t(2j+1) read in ph5-8;
//   W8 covers the 4 halves of t(2j+2) read in next ph1-4.
//   Last iteration: W4 = vmcnt(0), W8 skipped.
// Phase body (verified m201 template): reads; stage; barrier; lgkmcnt(0);
// setprio(1); 16 MFMA; setprio(0); [vmcnt]; barrier.
// MODE 1 (fused QKV): piece = col0>>10 (wave-uniform; 1024 % 256 == 0);
// pieces 0,1 -> compact [8192][1024] at C + piece*sC; piece 2 -> V
// transposed to Vt[b][d][2048], b = blockIdx.x>>3.
// ---------------------------------------------------------------------------
template <typename OutT, bool BIAS, int MODE>
__global__ __launch_bounds__(512, 2) void gemm8(
    const unsigned short* __restrict__ A,
    const unsigned short* __restrict__ Bt,
    OutT* __restrict__ C,
    unsigned short* __restrict__ Vt,
    const float* __restrict__ bias,
    int Kd, int lda, int ldb, int ldc,
    long sA, long sB, long sC,
    float scale) {
  constexpr int BBASE = 256 * 64;            // B region offset (ushorts)
  constexpr int BUF0 = 0, BUF1 = 2 * BBASE;  // 32768
  __shared__ unsigned short lds[4 * BBASE];  // 128 KB

  const int bz = blockIdx.z;
  A  += (size_t)bz * sA + (size_t)blockIdx.x * 256 * lda;
  Bt += (size_t)bz * sB + (size_t)blockIdx.y * 256 * ldb;

  const int tid  = threadIdx.x;
  const int wave = tid >> 6;
  const int lane = tid & 63;
  const int wm   = wave >> 2;              // 0..1  (128-row half)
  const int wn   = wave & 3;               // 0..3  (64-col strip)
  const int l15  = lane & 15;
  const int hi   = lane >> 4;              // 0..3
  // stage-side
  const int srow = tid >> 3;               // 0..63 within a call
  const int schk = ((tid & 7) ^ ((tid >> 3) & 7)) * 8;   // ushort offset
  // read-side offsets (ushorts)
  int aoff[2], boff[2];
#pragma unroll
  for (int ks = 0; ks < 2; ++ks) {
    const int slot = ((ks * 4 + hi) ^ (l15 & 7)) * 8;
    aoff[ks] = (wm * 128 + l15) * 64 + slot;
    boff[ks] = BBASE + ((wn >> 1) * 64 + (wn & 1) * 32 + l15) * 64 + slot;
  }

  auto stA = [&](int buf, int r0, int k0) {
    const unsigned short* g = A + (size_t)(r0 + srow) * lda + (k0 + schk);
    gload_lds16(g, &lds[buf + r0 * 64 + wave * 512]);
  };
  auto stB = [&](int buf, int lr0, int k0) {
    const int lr = lr0 + srow;
    const int gc = ((lr >> 6) & 1) * 128 + ((lr >> 5) & 1) * 64 +
                   (lr >> 7) * 32 + (lr & 31);
    const unsigned short* g = Bt + (size_t)gc * ldb + (k0 + schk);
    gload_lds16(g, &lds[buf + BBASE + lr0 * 64 + wave * 512]);
  };

  f32x4 acc[8][4] = {};
  bf16x8 af[4][2], bf0[2][2], bf1[2][2];

  auto dsA = [&](int buf, int mq) {
#pragma unroll
    for (int mf = 0; mf < 4; ++mf)
#pragma unroll
      for (int ks = 0; ks < 2; ++ks)
        af[mf][ks] = *(const bf16x8*)&lds[buf + (mq * 64 + mf * 16) * 64 + aoff[ks]];
  };
  auto dsB = [&](bf16x8 (&bf)[2][2], int buf, int nq) {
#pragma unroll
    for (int nf = 0; nf < 2; ++nf)
#pragma unroll
      for (int ks = 0; ks < 2; ++ks)
        bf[nf][ks] = *(const bf16x8*)&lds[buf + nq * 8192 + nf * 1024 + boff[ks]];
  };
  auto mmq = [&](bf16x8 (&bf)[2][2], int mq, int nq) {
#pragma unroll
    for (int mf = 0; mf < 4; ++mf)
#pragma unroll
      for (int nf = 0; nf < 2; ++nf) {
        f32x4* a = &acc[mq * 4 + mf][nq * 2 + nf];
        *a = MFMA16(af[mf][0], bf[nf][0], *a);
        *a = MFMA16(af[mf][1], bf[nf][1], *a);
      }
  };

  // prologue: t0 fully + t1 {A-mq0, B-nq1}; drain all.
  stA(BUF0, 0, 0);    stA(BUF0, 128, 0);    // t0 A-mq0
  stB(BUF0, 0, 0);    stB(BUF0, 64, 0);     // t0 B-nq0
  stB(BUF0, 128, 0);  stB(BUF0, 192, 0);    // t0 B-nq1
  stA(BUF0, 64, 0);   stA(BUF0, 192, 0);    // t0 A-mq1
  stA(BUF1, 0, 64);   stA(BUF1, 128, 64);   // t1 A-mq0
  stB(BUF1, 128, 64); stB(BUF1, 192, 64);   // t1 B-nq1
  VMCNT(0);
  BARRIER();

  const int NP = Kd >> 7;                    // iterations of 2 K-tiles
  for (int j = 0; j < NP; ++j) {
    const int k1 = ((2 * j + 1) << 6);
    const int k2 = k1 + 64, k3 = k1 + 128;
    const bool st = (j + 1) < NP;

    // ---- ph1: BUF0 (mq0, nq0) ----
    dsA(BUF0, 0); dsB(bf0, BUF0, 0);
    stA(BUF1, 64, k1); stA(BUF1, 192, k1);
    BARRIER(); LGKM0();
    __builtin_amdgcn_s_setprio(1); mmq(bf0, 0, 0); __builtin_amdgcn_s_setprio(0);
    BARRIER();
    // ---- ph2: (mq0, nq1) ----
    dsB(bf1, BUF0, 1);
    stB(BUF1, 0, k1); stB(BUF1, 64, k1);
    BARRIER(); LGKM0();
    __builtin_amdgcn_s_setprio(1); mmq(bf1, 0, 1); __builtin_amdgcn_s_setprio(0);
    BARRIER();
    // ---- ph3: (mq1, nq1) ----
    dsA(BUF0, 1);
    if (st) { stA(BUF0, 0, k2); stA(BUF0, 128, k2); }
    BARRIER(); LGKM0();
    __builtin_amdgcn_s_setprio(1); mmq(bf1, 1, 1); __builtin_amdgcn_s_setprio(0);
    BARRIER();
    // ---- ph4: (mq1, nq0) ----
    if (st) { stB(BUF0, 128, k2); stB(BUF0, 192, k2); }
    BARRIER(); LGKM0();
    __builtin_amdgcn_s_setprio(1); mmq(bf0, 1, 0); __builtin_amdgcn_s_setprio(0);
    if (st) { VMCNT(4); } else { VMCNT(0); }
    BARRIER();
    // ---- ph5: BUF1 (mq0, nq0) ----
    dsA(BUF1, 0); dsB(bf0, BUF1, 0);
    if (st) { stA(BUF0, 64, k2); stA(BUF0, 192, k2); }
    BARRIER(); LGKM0();
    __builtin_amdgcn_s_setprio(1); mmq(bf0, 0, 0); __builtin_amdgcn_s_setprio(0);
    BARRIER();
    // ---- ph6: (mq0, nq1) ----
    dsB(bf1, BUF1, 1);
    if (st) { stB(BUF0, 0, k2); stB(BUF0, 64, k2); }
    BARRIER(); LGKM0();
    __builtin_amdgcn_s_setprio(1); mmq(bf1, 0, 1); __builtin_amdgcn_s_setprio(0);
    BARRIER();
    // ---- ph7: (mq1, nq1) ----
    dsA(BUF1, 1);
    if (st) { stA(BUF1, 0, k3); stA(BUF1, 128, k3); }
    BARRIER(); LGKM0();
    __builtin_amdgcn_s_setprio(1); mmq(bf1, 1, 1); __builtin_amdgcn_s_setprio(0);
    BARRIER();
    // ---- ph8: (mq1, nq0) ----
    if (st) { stB(BUF1, 128, k3); stB(BUF1, 192, k3); }
    BARRIER(); LGKM0();
    __builtin_amdgcn_s_setprio(1); mmq(bf0, 1, 0); __builtin_amdgcn_s_setprio(0);
    if (st) { VMCNT(4); }
    BARRIER();
  }

  // ------------------------------- epilogue -------------------------------
  const int hi4  = hi << 2;
  const int row0 = blockIdx.x * 256 + wm * 128;
  const int col0 = blockIdx.y * 256 + wn * 64;

  if constexpr (MODE == 1) {
    const int piece = col0 >> 10;                 // wave-uniform
    float bvv[4];
#pragma unroll
    for (int nt = 0; nt < 4; ++nt)
      bvv[nt] = BIAS ? bias[col0 + nt * 16 + l15] : 0.0f;
    if (piece < 2) {
      OutT* dst = C + (size_t)piece * sC;
      const int cb = (col0 & 1023) + l15;
#pragma unroll
      for (int mt = 0; mt < 8; ++mt)
#pragma unroll
        for (int r = 0; r < 4; ++r) {
          const size_t rowoff = (size_t)(row0 + mt * 16 + hi4 + r) * ldc;
#pragma unroll
          for (int nt = 0; nt < 4; ++nt)
            dst[rowoff + cb + nt * 16] = (OutT)f2bf(acc[mt][nt][r] * scale + bvv[nt]);
        }
    } else {
      const int b = blockIdx.x >> 3;
      const int sb = (blockIdx.x & 7) * 256 + wm * 128 + hi4;
#pragma unroll
      for (int nt = 0; nt < 4; ++nt) {
        const int d = ((col0 + nt * 16) & 1023) + l15;
#pragma unroll
        for (int mt = 0; mt < 8; ++mt) {
          us4 pk;
          pk.x = f2bf(acc[mt][nt][0] * scale + bvv[nt]);
          pk.y = f2bf(acc[mt][nt][1] * scale + bvv[nt]);
          pk.z = f2bf(acc[mt][nt][2] * scale + bvv[nt]);
          pk.w = f2bf(acc[mt][nt][3] * scale + bvv[nt]);
          *(us4*)&Vt[((size_t)b << 21) + (size_t)d * 2048 + sb + mt * 16] = pk;
        }
      }
    }
  } else {
    C += (size_t)bz * sC;
    float bvv[4];
#pragma unroll
    for (int nt = 0; nt < 4; ++nt)
      bvv[nt] = BIAS ? bias[col0 + nt * 16 + l15] : 0.0f;
    const int cb = col0 + l15;
#pragma unroll
    for (int mt = 0; mt < 8; ++mt)
#pragma unroll
      for (int r = 0; r < 4; ++r) {
        const size_t rowoff = (size_t)(row0 + mt * 16 + hi4 + r) * ldc;
#pragma unroll
        for (int nt = 0; nt < 4; ++nt) {
          const float v = acc[mt][nt][r] * scale + bvv[nt];
          if constexpr (sizeof(OutT) == 4)
            C[rowoff + cb + nt * 16] = v;
          else
            C[rowoff + cb + nt * 16] = (OutT)f2bf(v);
        }
      }
  }
}

// ---------------------------------------------------------------------------
// gemmk: round-8's verified BM=128 x BN=128, BK=32, 4 waves of 64x64,
// 3-ring 48 KB -> 3 blk/CU.  Used for ctx and out (controls).
// ---------------------------------------------------------------------------
template <typename OutT, bool BIAS>
__global__ __launch_bounds__(256, 3) void gemmk(
    const unsigned short* __restrict__ A,
    const unsigned short* __restrict__ Bt,
    OutT* __restrict__ C,
    const float* __restrict__ bias,
    int Kd, int lda, int ldb, int ldc,
    long sA, long sB, long sC,
    float scale) {
  constexpr int ABUF  = 128 * 32;
  constexpr int BUFSZ = ABUF + 128 * 32;     // 8192 ushorts = 16 KB
  __shared__ unsigned short lds[3 * BUFSZ];  // 48 KB

  const int bz = blockIdx.z;
  A  += (size_t)bz * sA + (size_t)blockIdx.x * 128 * lda;
  Bt += (size_t)bz * sB + (size_t)blockIdx.y * 128 * ldb;

  const int tid  = threadIdx.x;
  const int wave = tid >> 6;
  const int lane = tid & 63;
  const int wm   = wave >> 1;
  const int wn   = wave & 1;
  const int l15  = lane & 15;
  const int hi   = lane >> 4;
  const int srow = tid >> 2;               // 0..63 per call
  const int schk = ((tid & 3) ^ ((tid >> 3) & 3)) * 8;

  auto stage = [&](int bi, int k0) {
    unsigned short* L = &lds[bi * BUFSZ + wave * 512];
    const unsigned short* ga = A + (size_t)srow * lda + (k0 + schk);
    gload_lds16(ga, L);
    gload_lds16(ga + (size_t)64 * lda, L + 2048);
    const unsigned short* gb = Bt + (size_t)srow * ldb + (k0 + schk);
    gload_lds16(gb, L + ABUF);
    gload_lds16(gb + (size_t)64 * ldb, L + ABUF + 2048);
  };

  f32x4 acc[4][4] = {};
  stage(0, 0);
  stage(1, 32);
  VMCNT(4);
  BARRIER();

  const int NT = Kd >> 5;
  int bufi = 0;
  const int xh  = (hi ^ ((l15 >> 1) & 3)) * 8;
  const int rdA = (wm * 64 + l15) * 32 + xh;
  const int rdB = ABUF + (wn * 64 + l15) * 32 + xh;
  for (int t = 0; t < NT; ++t) {
    if (t + 2 < NT) {
      int nbi = bufi + 2; if (nbi >= 3) nbi -= 3;
      stage(nbi, (t + 2) << 5);
    }
    const unsigned short* L = &lds[bufi * BUFSZ];
    bf16x8 af[4], bf[4];
#pragma unroll
    for (int mt = 0; mt < 4; ++mt)
      af[mt] = *(const bf16x8*)&L[rdA + mt * 512];
#pragma unroll
    for (int nt = 0; nt < 4; ++nt)
      bf[nt] = *(const bf16x8*)&L[rdB + nt * 512];
    __builtin_amdgcn_s_setprio(1);
#pragma unroll
    for (int mt = 0; mt < 4; ++mt)
#pragma unroll
      for (int nt = 0; nt < 4; ++nt)
        acc[mt][nt] = MFMA16(af[mt], bf[nt], acc[mt][nt]);
    __builtin_amdgcn_s_setprio(0);
    if (t + 2 < NT)      { VMCNT(4); }
    else if (t + 1 < NT) { VMCNT(0); }
    BARRIER();
    bufi = (bufi + 1 == 3) ? 0 : bufi + 1;
  }

  const int hi4  = hi << 2;
  const int row0 = blockIdx.x * 128 + wm * 64;
  const int col0 = blockIdx.y * 128 + wn * 64;
  C += (size_t)bz * sC;
  float bvv[4];
#pragma unroll
  for (int nt = 0; nt < 4; ++nt)
    bvv[nt] = BIAS ? bias[col0 + nt * 16 + l15] : 0.0f;
  const int cb = col0 + l15;
#pragma unroll
  for (int mt = 0; mt < 4; ++mt)
#pragma unroll
    for (int r = 0; r < 4; ++r) {
      const size_t rowoff = (size_t)(row0 + mt * 16 + hi4 + r) * ldc;
#pragma unroll
      for (int nt = 0; nt < 4; ++nt) {
        const float v = acc[mt][nt][r] * scale + bvv[nt];
        if constexpr (sizeof(OutT) == 4)
          C[rowoff + cb + nt * 16] = v;
        else
          C[rowoff + cb + nt * 16] = (OutT)f2bf(v);
      }
    }
}

// fp32 -> bf16 flat convert (4 elems/thread)
__global__ void cvt_x(const float* __restrict__ in, unsigned short* __restrict__ out, int n4) {
  const int i = blockIdx.x * blockDim.x + threadIdx.x;
  if (i < n4) {
    const float4 v = ((const float4*)in)[i];
    uint2 o;
    o.x = (unsigned)f2bf(v.x) | ((unsigned)f2bf(v.y) << 16);
    o.y = (unsigned)f2bf(v.z) | ((unsigned)f2bf(v.w) << 16);
    ((uint2*)out)[i] = o;
  }
}

// All 4 weight matrices (1024x1024 fp32) -> bf16 transposed, one launch.
__global__ void cvtT_w4(const float* __restrict__ Wq, const float* __restrict__ Wk,
                        const float* __restrict__ Wv, const float* __restrict__ Wo,
                        unsigned short* __restrict__ Wqkvb, unsigned short* __restrict__ Wob) {
  __shared__ unsigned short tile[64][65];
  const int z = blockIdx.z;
  const float* in = (z == 0) ? Wq : (z == 1) ? Wk : (z == 2) ? Wv : Wo;
  unsigned short* out = (z == 3) ? Wob : Wqkvb + (size_t)z * 1024 * 1024;
  const int r0 = blockIdx.y * 64, c0 = blockIdx.x * 64;
  for (int i = threadIdx.y; i < 64; i += 4)
    tile[i][threadIdx.x] = f2bf(in[(size_t)(r0 + i) * 1024 + c0 + threadIdx.x]);
  __syncthreads();
  for (int i = threadIdx.y; i < 64; i += 4)
    out[(size_t)(c0 + i) * 1024 + r0 + threadIdx.x] = tile[threadIdx.x][i];
}

// concat bq|bk|bv into bqkv
__global__ void concat_bias(const float* __restrict__ bq, const float* __restrict__ bk,
                            const float* __restrict__ bv, float* __restrict__ dst) {
  const int z = blockIdx.x;
  const float* src = (z == 0) ? bq : (z == 1) ? bk : bv;
  const int i = threadIdx.x;
  ((float4*)(dst + z * 1024))[i] = ((const float4*)src)[i];
}

// Softmax, one WAVE per 2048-elem bf16 row, pure shfl, no barriers.
__global__ __launch_bounds__(512) void softmax_w(unsigned short* __restrict__ scores) {
  const int lane = threadIdx.x & 63;
  unsigned short* p =
      scores + ((size_t)blockIdx.x * 8 + (threadIdx.x >> 6)) * 2048;
  uint4 raw[4];
  float v[32];
#pragma unroll
  for (int g = 0; g < 4; ++g) raw[g] = ((const uint4*)p)[lane + g * 64];
#pragma unroll
  for (int g = 0; g < 4; ++g) {
    v[g * 8 + 0] = __uint_as_float(raw[g].x << 16);
    v[g * 8 + 1] = __uint_as_float(raw[g].x & 0xffff0000u);
    v[g * 8 + 2] = __uint_as_float(raw[g].y << 16);
    v[g * 8 + 3] = __uint_as_float(raw[g].y & 0xffff0000u);
    v[g * 8 + 4] = __uint_as_float(raw[g].z << 16);
    v[g * 8 + 5] = __uint_as_float(raw[g].z & 0xffff0000u);
    v[g * 8 + 6] = __uint_as_float(raw[g].w << 16);
    v[g * 8 + 7] = __uint_as_float(raw[g].w & 0xffff0000u);
  }
  float m = v[0];
#pragma unroll
  for (int i = 1; i < 32; ++i) m = fmaxf(m, v[i]);
#pragma unroll
  for (int off = 32; off; off >>= 1) m = fmaxf(m, __shfl_xor(m, off, 64));
  float s = 0.f;
#pragma unroll
  for (int i = 0; i < 32; ++i) { v[i] = __expf(v[i] - m); s += v[i]; }
#pragma unroll
  for (int off = 32; off; off >>= 1) s += __shfl_xor(s, off, 64);
  const float inv = 1.0f / s;
#pragma unroll
  for (int g = 0; g < 4; ++g) {
    uint4 ov;
    ov.x = (unsigned)f2bf(v[g * 8 + 0] * inv) | ((unsigned)f2bf(v[g * 8 + 1] * inv) << 16);
    ov.y = (unsigned)f2bf(v[g * 8 + 2] * inv) | ((unsigned)f2bf(v[g * 8 + 3] * inv) << 16);
    ov.z = (unsigned)f2bf(v[g * 8 + 4] * inv) | ((unsigned)f2bf(v[g * 8 + 5] * inv) << 16);
    ov.w = (unsigned)f2bf(v[g * 8 + 6] * inv) | ((unsigned)f2bf(v[g * 8 + 7] * inv) << 16);
    ((uint4*)p)[lane + g * 64] = ov;
  }
}

// ---------------------------------------------------------------------------
extern "C" void kernel_launch(void* const* d_in, const int* in_sizes, int n_in,
                              void* d_out, int out_size, void* d_ws, size_t ws_size,
                              hipStream_t stream) {
  const float* x  = (const float*)d_in[0];
  const float* Wq = (const float*)d_in[1];
  const float* bq = (const float*)d_in[2];
  const float* Wk = (const float*)d_in[3];
  const float* bk = (const float*)d_in[4];
  const float* Wv = (const float*)d_in[5];
  const float* bv = (const float*)d_in[6];
  const float* Wo = (const float*)d_in[7];
  const float* bo = (const float*)d_in[8];
  float* out = (float*)d_out;

  char* ws = (char*)d_ws;
  size_t off = 0;
  auto alloc = [&](size_t bytes) { char* p = ws + off; off += (bytes + 255) & ~255UL; return p; };
  unsigned short* xb    = (unsigned short*)alloc(8192UL * 1024 * 2);     // 16 MiB
  unsigned short* Wqkvb = (unsigned short*)alloc(3072UL * 1024 * 2);     // 6 MiB
  unsigned short* Wob   = (unsigned short*)alloc(1024UL * 1024 * 2);     // 2 MiB
  float*          bqkv  = (float*)alloc(3072UL * 4);
  unsigned short* Qb    = (unsigned short*)alloc(8192UL * 1024 * 2);     // 16 MiB (piece 0)
  unsigned short* Kb    = (unsigned short*)alloc(8192UL * 1024 * 2);     // 16 MiB (piece 1)
  unsigned short* Vtb   = (unsigned short*)alloc(4UL * 1024 * 2048 * 2); // 16 MiB [b][d][s]
  unsigned short* attn  = (unsigned short*)alloc(8192UL * 2048 * 2);     // 32 MiB bf16 scores
  unsigned short* ctxb  = (unsigned short*)alloc(8192UL * 1024 * 2);     // 16 MiB

  // input convert + all weight transposes + bias concat
  cvt_x<<<2097152 / 256, 256, 0, stream>>>(x, xb, 2097152);
  cvtT_w4<<<dim3(16, 16, 4), dim3(64, 4), 0, stream>>>(Wq, Wk, Wv, Wo, Wqkvb, Wob);
  concat_bias<<<3, 256, 0, stream>>>(bq, bk, bv, bqkv);

  // fused QKV projection (8-phase 256x256): 384 blocks.
  gemm8<unsigned short, true, 1><<<dim3(32, 12, 1), 512, 0, stream>>>(
      xb, Wqkvb, Qb, Vtb, bqkv, 1024, 1024, 1024, 1024, 0, 0, 8192L * 1024, 1.0f);

  // scores = (Q @ K^T) / 32 -> bf16 (8-phase): 256 blocks = 1 exact round.
  gemm8<unsigned short, false, 0><<<dim3(8, 8, 4), 512, 0, stream>>>(
      Qb, Kb, attn, nullptr, nullptr, 1024, 1024, 1024, 2048,
      2048L * 1024, 2048L * 1024, 2048L * 2048, 0.03125f);

  // softmax: one wave per row. 1024 blocks.
  softmax_w<<<1024, 512, 0, stream>>>(attn);

  // ctx = attn @ V (round-8 BM=128 kernel). 512 blocks.
  gemmk<unsigned short, false><<<dim3(16, 8, 4), 256, 0, stream>>>(
      attn, Vtb, ctxb, nullptr, 2048, 2048, 2048, 1024,
      2048L * 2048, 1024L * 2048, 2048L * 1024, 1.0f);

  // out = ctx @ Wo + bo (fp32 out). 512 blocks.
  gemmk<float, true><<<dim3(64, 8, 1), 256, 0, stream>>>(
      ctxb, Wob, out, bo, 1024, 1024, 1024, 1024, 0, 0, 0, 1.0f);
}

// Round 11
// 286.149 us; speedup vs baseline: 1.0259x; 1.0208x over previous
//
#include <hip/hip_runtime.h>

typedef __attribute__((ext_vector_type(8))) short bf16x8;
typedef __attribute__((ext_vector_type(4))) float f32x4;
typedef __attribute__((ext_vector_type(4))) unsigned short us4;

#define AS1 __attribute__((address_space(1)))
#define AS3 __attribute__((address_space(3)))

__device__ __forceinline__ unsigned short f2bf(float f) {
  unsigned u = __float_as_uint(f);
  u += 0x7fff + ((u >> 16) & 1);   // RNE
  return (unsigned short)(u >> 16);
}

__device__ __forceinline__ void gload_lds16(const void* g, void* l) {
  __builtin_amdgcn_global_load_lds((const AS1 unsigned int*)g,
                                   (AS3 unsigned int*)l, 16, 0, 0);
}

#define MFMA16(a, b, c) __builtin_amdgcn_mfma_f32_16x16x32_bf16(a, b, c, 0, 0, 0)

// ---------------------------------------------------------------------------
// BM (template: 256 or 128) x BN=128, BK=32 bf16 GEMM, one window per K-tile,
// 3-deep LDS ring.  C[M,N] = scale*(A[M,K] @ Bt[N,K]^T) + bias.
// THREADS = 2*BM (512 or 256) = 8 or 4 waves (wm=wave>>1, wn=wave&1);
// per-wave 64x64 = acc[4][4] of 16x16x32 MFMA.
//   BM=256: LDS 72 KB -> 2 blocks/CU.   BM=128: LDS 48 KB -> 3 blocks/CU.
// Round-11: QKV switched to BM=128 so its grid (64x24 = 1536 blocks) packs
// EXACTLY 2.0 occupancy rounds (768 slots), vs BM=256's 1.5-round tax.
//
// LDS layout (round-7, verified 0 conflicts + coalesced staging): row-major
// 16-row x 32-col fragment blocks (1 KB); 16B chunk index XORed with
// g(row) = (row>>1)&3.
// Stage (one gload/thread per call of RPC = THREADS/4 rows): lane tid fetches
//   global row = tid>>2, chunk = (tid&3) ^ ((tid>>3)&3)  [== g(row)]
//   -> each 4-lane quad covers one full (permuted) 64B line => coalesced;
//   LDS dest = base + tid*16B (linear, rule 21).
// Read: lane (l15, hi) reads block offset l15*64B + (hi ^ g(l15))*16B
//   -> same bank distribution as linear (verified SQ_LDS_BANK_CONFLICT=0).
// Calls/tile: A: BM/RPC = 2, B: 128/RPC = 1 or 2 -> LOADS = 3 / 4.
//
// Window t: stage(t+2) [LOADS gloads] ; ds_read af[4], bf[4] of tile t ;
// 16 MFMA ; vmcnt(LOADS) ; s_barrier.
//   Steady state at wait: outstanding = 2*LOADS -> vmcnt(LOADS) drains
//   exactly stage(t+1), one full window ahead of its reads.  Per-wave vmcnt
//   + barrier => tile complete CU-wide.  Tail: t+2==NT -> vmcnt(0); last
//   window -> no wait.
// WAR: stage(t+2) overwrites buf[(t-1)%3]; its ds_reads were lgkm-drained
// before window t-1's MFMAs, then the end-of-(t-1) barrier was crossed.
//
// MODE 0: C[bz*sC + row*ldc + col].  MODE 1 (fused QKV): piece = col0>>10
// (wave-uniform); pieces 0,1 -> compact [8192][1024] at C + piece*sC;
// piece 2 -> V transposed to Vt[b][d][2048], b = blockIdx.x/(2048/BM).
// ---------------------------------------------------------------------------
template <typename OutT, bool BIAS, int MODE, int BM>
__global__ __launch_bounds__(2 * BM, (BM == 256) ? 2 : 3) void gemmk(
    const unsigned short* __restrict__ A,
    const unsigned short* __restrict__ Bt,
    OutT* __restrict__ C,
    unsigned short* __restrict__ Vt,
    const float* __restrict__ bias,
    int Kd, int lda, int ldb, int ldc,
    long sA, long sB, long sC,
    float scale) {
  constexpr int ABUF  = BM * 32;             // ushorts
  constexpr int BUFSZ = ABUF + 128 * 32;     // ushorts
  __shared__ unsigned short lds[3 * BUFSZ];  // 72 KB / 48 KB

  const int bz = blockIdx.z;
  A  += (size_t)bz * sA + (size_t)blockIdx.x * BM * lda;
  Bt += (size_t)bz * sB + (size_t)blockIdx.y * 128 * ldb;

  const int tid  = threadIdx.x;
  const int wave = tid >> 6;
  const int lane = tid & 63;
  const int wm   = wave >> 1;              // 0..3 / 0..1
  const int wn   = wave & 1;               // 0..1
  const int l15  = lane & 15;
  const int hi   = lane >> 4;              // 0..3
  // stage-side: lane covers global (row = tid>>2, chunk = (tid&3)^g(row))
  const int srow = tid >> 2;               // 0..THREADS/4-1 within a call
  const int schk = ((tid & 3) ^ ((tid >> 3) & 3)) * 8;  // ushort offset

  auto stage = [&](int bi, int k0) {
    unsigned short* L = &lds[bi * BUFSZ + wave * 512];       // wave-uniform
    const unsigned short* ga = A + (size_t)srow * lda + (k0 + schk);
    const unsigned short* gb = Bt + (size_t)srow * ldb + (k0 + schk);
    if constexpr (BM == 256) {
      gload_lds16(ga, L);                                    // A rows 0-127
      gload_lds16(ga + (size_t)128 * lda, L + 4096);         // A rows 128-255
      gload_lds16(gb, L + ABUF);                             // B rows 0-127
    } else {
      gload_lds16(ga, L);                                    // A rows 0-63
      gload_lds16(ga + (size_t)64 * lda, L + 2048);          // A rows 64-127
      gload_lds16(gb, L + ABUF);                             // B rows 0-63
      gload_lds16(gb + (size_t)64 * ldb, L + ABUF + 2048);   // B rows 64-127
    }
  };

  f32x4 acc[4][4] = {};

  // prologue: stage tiles 0,1; drain tile 0 (keep tile 1 in flight)
  stage(0, 0);
  stage(1, 32);
  if constexpr (BM == 256) asm volatile("s_waitcnt vmcnt(3)" ::: "memory");
  else                     asm volatile("s_waitcnt vmcnt(4)" ::: "memory");
  __builtin_amdgcn_s_barrier();

  const int NT = Kd >> 5;
  int bufi = 0;
  // read-side swizzled chunk offset: (hi ^ g(l15)) * 8 ushorts
  const int xh  = (hi ^ ((l15 >> 1) & 3)) * 8;
  const int rdA = (wm * 64 + l15) * 32 + xh;          // + mt*512
  const int rdB = ABUF + (wn * 64 + l15) * 32 + xh;   // + nt*512
  for (int t = 0; t < NT; ++t) {
    if (t + 2 < NT) {
      int nbi = bufi + 2; if (nbi >= 3) nbi -= 3;
      stage(nbi, (t + 2) << 5);
    }
    const unsigned short* L = &lds[bufi * BUFSZ];
    bf16x8 af[4], bf[4];
#pragma unroll
    for (int mt = 0; mt < 4; ++mt)
      af[mt] = *(const bf16x8*)&L[rdA + mt * 512];
#pragma unroll
    for (int nt = 0; nt < 4; ++nt)
      bf[nt] = *(const bf16x8*)&L[rdB + nt * 512];
    __builtin_amdgcn_s_setprio(1);
#pragma unroll
    for (int mt = 0; mt < 4; ++mt)
#pragma unroll
      for (int nt = 0; nt < 4; ++nt)
        acc[mt][nt] = MFMA16(af[mt], bf[nt], acc[mt][nt]);
    __builtin_amdgcn_s_setprio(0);
    if (t + 2 < NT) {
      if constexpr (BM == 256) asm volatile("s_waitcnt vmcnt(3)" ::: "memory");
      else                     asm volatile("s_waitcnt vmcnt(4)" ::: "memory");
    } else if (t + 1 < NT) {
      asm volatile("s_waitcnt vmcnt(0)" ::: "memory");
    }
    __builtin_amdgcn_s_barrier();
    bufi = (bufi + 1 == 3) ? 0 : bufi + 1;
  }

  // ------------------------------- epilogue -------------------------------
  const int hi4  = hi << 2;
  const int row0 = blockIdx.x * BM + wm * 64;
  const int col0 = blockIdx.y * 128 + wn * 64;

  if constexpr (MODE == 1) {
    const int piece = col0 >> 10;                 // wave-uniform
    float bvv[4];
#pragma unroll
    for (int nt = 0; nt < 4; ++nt)
      bvv[nt] = BIAS ? bias[col0 + nt * 16 + l15] : 0.0f;
    if (piece < 2) {
      OutT* dst = C + (size_t)piece * sC;
      const int cb = (col0 & 1023) + l15;
#pragma unroll
      for (int mt = 0; mt < 4; ++mt)
#pragma unroll
        for (int r = 0; r < 4; ++r) {
          const size_t rowoff = (size_t)(row0 + mt * 16 + hi4 + r) * ldc;
#pragma unroll
          for (int nt = 0; nt < 4; ++nt)
            dst[rowoff + cb + nt * 16] = (OutT)f2bf(acc[mt][nt][r] * scale + bvv[nt]);
        }
    } else {
      // V piece: write transposed Vt[b][d][2048]
      constexpr int BPB = 2048 / BM;              // blocks per batch
      const int b = blockIdx.x / BPB;
      const int sb = (blockIdx.x % BPB) * BM + wm * 64 + hi4;
#pragma unroll
      for (int nt = 0; nt < 4; ++nt) {
        const int d = ((col0 + nt * 16) & 1023) + l15;
#pragma unroll
        for (int mt = 0; mt < 4; ++mt) {
          us4 pk;
          pk.x = f2bf(acc[mt][nt][0] * scale + bvv[nt]);
          pk.y = f2bf(acc[mt][nt][1] * scale + bvv[nt]);
          pk.z = f2bf(acc[mt][nt][2] * scale + bvv[nt]);
          pk.w = f2bf(acc[mt][nt][3] * scale + bvv[nt]);
          *(us4*)&Vt[((size_t)b << 21) + (size_t)d * 2048 + sb + mt * 16] = pk;
        }
      }
    }
  } else {
    C += (size_t)bz * sC;
    float bvv[4];
#pragma unroll
    for (int nt = 0; nt < 4; ++nt)
      bvv[nt] = BIAS ? bias[col0 + nt * 16 + l15] : 0.0f;
    const int cb = col0 + l15;
#pragma unroll
    for (int mt = 0; mt < 4; ++mt)
#pragma unroll
      for (int r = 0; r < 4; ++r) {
        const size_t rowoff = (size_t)(row0 + mt * 16 + hi4 + r) * ldc;
#pragma unroll
        for (int nt = 0; nt < 4; ++nt) {
          const float v = acc[mt][nt][r] * scale + bvv[nt];
          if constexpr (sizeof(OutT) == 4)
            C[rowoff + cb + nt * 16] = v;
          else
            C[rowoff + cb + nt * 16] = (OutT)f2bf(v);
        }
      }
  }
}

// fp32 -> bf16 flat convert (4 elems/thread)
__global__ void cvt_x(const float* __restrict__ in, unsigned short* __restrict__ out, int n4) {
  const int i = blockIdx.x * blockDim.x + threadIdx.x;
  if (i < n4) {
    const float4 v = ((const float4*)in)[i];
    uint2 o;
    o.x = (unsigned)f2bf(v.x) | ((unsigned)f2bf(v.y) << 16);
    o.y = (unsigned)f2bf(v.z) | ((unsigned)f2bf(v.w) << 16);
    ((uint2*)out)[i] = o;
  }
}

// All 4 weight matrices (1024x1024 fp32) -> bf16 transposed, one launch.
__global__ void cvtT_w4(const float* __restrict__ Wq, const float* __restrict__ Wk,
                        const float* __restrict__ Wv, const float* __restrict__ Wo,
                        unsigned short* __restrict__ Wqkvb, unsigned short* __restrict__ Wob) {
  __shared__ unsigned short tile[64][65];
  const int z = blockIdx.z;
  const float* in = (z == 0) ? Wq : (z == 1) ? Wk : (z == 2) ? Wv : Wo;
  unsigned short* out = (z == 3) ? Wob : Wqkvb + (size_t)z * 1024 * 1024;
  const int r0 = blockIdx.y * 64, c0 = blockIdx.x * 64;
  for (int i = threadIdx.y; i < 64; i += 4)
    tile[i][threadIdx.x] = f2bf(in[(size_t)(r0 + i) * 1024 + c0 + threadIdx.x]);
  __syncthreads();
  for (int i = threadIdx.y; i < 64; i += 4)
    out[(size_t)(c0 + i) * 1024 + r0 + threadIdx.x] = tile[threadIdx.x][i];
}

// concat bq|bk|bv into bqkv
__global__ void concat_bias(const float* __restrict__ bq, const float* __restrict__ bk,
                            const float* __restrict__ bv, float* __restrict__ dst) {
  const int z = blockIdx.x;
  const float* src = (z == 0) ? bq : (z == 1) ? bk : bv;
  const int i = threadIdx.x;
  ((float4*)(dst + z * 1024))[i] = ((const float4*)src)[i];
}

// Softmax, one WAVE per 2048-elem bf16 row (lane holds 32 elems), pure
// shfl reductions: no LDS, no barriers. 8 rows per 512-thr block.
__global__ __launch_bounds__(512) void softmax_w(unsigned short* __restrict__ scores) {
  const int lane = threadIdx.x & 63;
  unsigned short* p =
      scores + ((size_t)blockIdx.x * 8 + (threadIdx.x >> 6)) * 2048;
  uint4 raw[4];
  float v[32];
#pragma unroll
  for (int g = 0; g < 4; ++g) raw[g] = ((const uint4*)p)[lane + g * 64];
#pragma unroll
  for (int g = 0; g < 4; ++g) {
    v[g * 8 + 0] = __uint_as_float(raw[g].x << 16);
    v[g * 8 + 1] = __uint_as_float(raw[g].x & 0xffff0000u);
    v[g * 8 + 2] = __uint_as_float(raw[g].y << 16);
    v[g * 8 + 3] = __uint_as_float(raw[g].y & 0xffff0000u);
    v[g * 8 + 4] = __uint_as_float(raw[g].z << 16);
    v[g * 8 + 5] = __uint_as_float(raw[g].z & 0xffff0000u);
    v[g * 8 + 6] = __uint_as_float(raw[g].w << 16);
    v[g * 8 + 7] = __uint_as_float(raw[g].w & 0xffff0000u);
  }
  float m = v[0];
#pragma unroll
  for (int i = 1; i < 32; ++i) m = fmaxf(m, v[i]);
#pragma unroll
  for (int off = 32; off; off >>= 1) m = fmaxf(m, __shfl_xor(m, off, 64));
  float s = 0.f;
#pragma unroll
  for (int i = 0; i < 32; ++i) { v[i] = __expf(v[i] - m); s += v[i]; }
#pragma unroll
  for (int off = 32; off; off >>= 1) s += __shfl_xor(s, off, 64);
  const float inv = 1.0f / s;
#pragma unroll
  for (int g = 0; g < 4; ++g) {
    uint4 ov;
    ov.x = (unsigned)f2bf(v[g * 8 + 0] * inv) | ((unsigned)f2bf(v[g * 8 + 1] * inv) << 16);
    ov.y = (unsigned)f2bf(v[g * 8 + 2] * inv) | ((unsigned)f2bf(v[g * 8 + 3] * inv) << 16);
    ov.z = (unsigned)f2bf(v[g * 8 + 4] * inv) | ((unsigned)f2bf(v[g * 8 + 5] * inv) << 16);
    ov.w = (unsigned)f2bf(v[g * 8 + 6] * inv) | ((unsigned)f2bf(v[g * 8 + 7] * inv) << 16);
    ((uint4*)p)[lane + g * 64] = ov;
  }
}

// ---------------------------------------------------------------------------
extern "C" void kernel_launch(void* const* d_in, const int* in_sizes, int n_in,
                              void* d_out, int out_size, void* d_ws, size_t ws_size,
                              hipStream_t stream) {
  const float* x  = (const float*)d_in[0];
  const float* Wq = (const float*)d_in[1];
  const float* bq = (const float*)d_in[2];
  const float* Wk = (const float*)d_in[3];
  const float* bk = (const float*)d_in[4];
  const float* Wv = (const float*)d_in[5];
  const float* bv = (const float*)d_in[6];
  const float* Wo = (const float*)d_in[7];
  const float* bo = (const float*)d_in[8];
  float* out = (float*)d_out;

  char* ws = (char*)d_ws;
  size_t off = 0;
  auto alloc = [&](size_t bytes) { char* p = ws + off; off += (bytes + 255) & ~255UL; return p; };
  unsigned short* xb    = (unsigned short*)alloc(8192UL * 1024 * 2);     // 16 MiB
  unsigned short* Wqkvb = (unsigned short*)alloc(3072UL * 1024 * 2);     // 6 MiB
  unsigned short* Wob   = (unsigned short*)alloc(1024UL * 1024 * 2);     // 2 MiB
  float*          bqkv  = (float*)alloc(3072UL * 4);
  unsigned short* Qb    = (unsigned short*)alloc(8192UL * 1024 * 2);     // 16 MiB (piece 0)
  unsigned short* Kb    = (unsigned short*)alloc(8192UL * 1024 * 2);     // 16 MiB (piece 1, == Qb + sC)
  unsigned short* Vtb   = (unsigned short*)alloc(4UL * 1024 * 2048 * 2); // 16 MiB [b][d][s]
  unsigned short* attn  = (unsigned short*)alloc(8192UL * 2048 * 2);     // 32 MiB bf16 scores
  unsigned short* ctxb  = (unsigned short*)alloc(8192UL * 1024 * 2);     // 16 MiB

  // input convert + all weight transposes + bias concat
  cvt_x<<<2097152 / 256, 256, 0, stream>>>(x, xb, 2097152);
  cvtT_w4<<<dim3(16, 16, 4), dim3(64, 4), 0, stream>>>(Wq, Wk, Wv, Wo, Wqkvb, Wob);
  concat_bias<<<3, 256, 0, stream>>>(bq, bk, bv, bqkv);

  // fused QKV projection: BM=128 -> 1536 blocks = exactly 2.0 rounds @3/CU.
  gemmk<unsigned short, true, 1, 128><<<dim3(64, 24, 1), 256, 0, stream>>>(
      xb, Wqkvb, Qb, Vtb, bqkv, 1024, 1024, 1024, 1024, 0, 0, 8192L * 1024, 1.0f);

  // scores = (Q @ K^T) / 32 -> bf16, per batch. 512 blocks = 1 round @2/CU.
  gemmk<unsigned short, false, 0, 256><<<dim3(8, 16, 4), 512, 0, stream>>>(
      Qb, Kb, attn, nullptr, nullptr, 1024, 1024, 1024, 2048,
      2048L * 1024, 2048L * 1024, 2048L * 2048, 0.03125f);

  // softmax: one wave per row, 8 rows/block, no barriers. 1024 blocks.
  softmax_w<<<1024, 512, 0, stream>>>(attn);

  // ctx = attn @ V (attn lda=2048, Vt is Bt layout). BM=128: 512 blocks.
  gemmk<unsigned short, false, 0, 128><<<dim3(16, 8, 4), 256, 0, stream>>>(
      attn, Vtb, ctxb, nullptr, nullptr, 2048, 2048, 2048, 1024,
      2048L * 2048, 1024L * 2048, 2048L * 1024, 1.0f);

  // out = ctx @ Wo + bo (fp32 out). BM=128: 512 blocks.
  gemmk<float, true, 0, 128><<<dim3(64, 8, 1), 256, 0, stream>>>(
      ctxb, Wob, out, nullptr, bo, 1024, 1024, 1024, 1024, 0, 0, 0, 1.0f);
}